// Round 6
// baseline (841.371 us; speedup 1.0000x reference)
//
#include <hip/hip_runtime.h>
#include <hip/hip_bf16.h>
#include <math.h>

#define DI __device__ __forceinline__

constexpr int cB = 64, cL = 256, cD = 768;
constexpr long BLD = (long)cB * cL * cD;   // 12,582,912
constexpr long BLL = (long)cB * cL * cL;   //  4,194,304
constexpr long cLL = (long)cL * cL;
constexpr long cLD = (long)cL * cD;

typedef __attribute__((ext_vector_type(8))) short b8;
typedef __attribute__((ext_vector_type(4))) float f4;

// async global->LDS, 16B per lane, dest = wave-uniform base + lane*16 (linear)
#define GLDS(g, l)                                                    \
  __builtin_amdgcn_global_load_lds(                                   \
      (const __attribute__((address_space(1))) void*)(g),             \
      (__attribute__((address_space(3))) void*)(l), 16, 0, 0)

// ---------------- reductions (wave64) ----------------
DI float wsum(float v) {
#pragma unroll
  for (int o = 32; o > 0; o >>= 1) v += __shfl_down(v, o, 64);
  return v;
}
DI float wsum_all(float v) {
#pragma unroll
  for (int m = 32; m > 0; m >>= 1) v += __shfl_xor(v, m, 64);
  return v;
}
DI float wmaxr(float v) {
#pragma unroll
  for (int o = 32; o > 0; o >>= 1) v = fmaxf(v, __shfl_down(v, o, 64));
  return v;
}
DI float blockSum(float v) {
  __shared__ float sh[4];
  v = wsum(v);
  __syncthreads();
  if ((threadIdx.x & 63) == 0) sh[threadIdx.x >> 6] = v;
  __syncthreads();
  return sh[0] + sh[1] + sh[2] + sh[3];
}
DI float blockMax(float v) {
  __shared__ float sh[4];
  v = wmaxr(v);
  __syncthreads();
  if ((threadIdx.x & 63) == 0) sh[threadIdx.x >> 6] = v;
  __syncthreads();
  return fmaxf(fmaxf(sh[0], sh[1]), fmaxf(sh[2], sh[3]));
}
DI float sigf(float x) { return 1.f / (1.f + expf(-x)); }

// ================= bf16 MFMA GEMM: C = A(MxK) @ BT(NxK)^T =================
// 128x128 tile, 4 waves, 4x4 of 16x16x32 frags/wave, BK=32.
// Staging via global_load_lds width=16; linear LDS [128][32] per tile.
// SWZ: XCD-contiguous tile remap (T1) — requires gridDim.x*gridDim.y % 8 == 0.
// EPI: 0=plain (OBF/RELU), 2=H-update (gate vs bf16 H in auxb; optional f32 out),
//      4=transposed bf16 write (per-256-row batch).
template <int OBF, int RELU, int BIAS, int EPI, int SWZ>
__global__ __launch_bounds__(256, 2) void bgemm(
    const __hip_bfloat16* __restrict__ A, const __hip_bfloat16* __restrict__ BT,
    void* __restrict__ Cv, const float* __restrict__ bias,
    float* __restrict__ auxf, __hip_bfloat16* __restrict__ auxb,
    int K, int lda, int ldb, int ldc,
    int zshift, int zmask, long sA1, long sA2, long sB1, long sB2, long sC,
    int czdiv) {
  __shared__ __hip_bfloat16 Asp[128 * 32];
  __shared__ __hip_bfloat16 Bsp[128 * 32];
  int bx = blockIdx.x, by = blockIdx.y;
  if (SWZ) {
    int gx = gridDim.x;
    int nb = gx * gridDim.y;
    int id = by * gx + bx;
    int cpx = nb >> 3;
    id = (id & 7) * cpx + (id >> 3);  // XCD k executes contiguous chunk k
    bx = id % gx;
    by = id / gx;
  }
  int z = blockIdx.z;
  A += (long)(z >> zshift) * sA1 + (long)(z & zmask) * sA2;
  BT += (long)(z >> zshift) * sB1 + (long)(z & zmask) * sB2;
  int tid = threadIdx.x;
  int lane = tid & 63, w = tid >> 6;
  int wr = w >> 1, wc = w & 1;
  int l16 = lane & 15, q = lane >> 4;
  int m0 = by << 7, n0 = bx << 7;

  int fm = tid >> 2, fq = tid & 3;
  const __hip_bfloat16* Ap0 = A + (long)(m0 + fm) * lda + fq * 8;
  const __hip_bfloat16* Ap1 = A + (long)(m0 + fm + 64) * lda + fq * 8;
  const __hip_bfloat16* Bp0 = BT + (long)(n0 + fm) * ldb + fq * 8;
  const __hip_bfloat16* Bp1 = BT + (long)(n0 + fm + 64) * ldb + fq * 8;
  char* Aw0 = (char*)Asp + (w << 10);
  char* Aw1 = (char*)Asp + 4096 + (w << 10);
  char* Bw0 = (char*)Bsp + (w << 10);
  char* Bw1 = (char*)Bsp + 4096 + (w << 10);

  f4 acc[4][4];
#pragma unroll
  for (int i = 0; i < 4; i++)
#pragma unroll
    for (int j = 0; j < 4; j++) acc[i][j] = (f4){0.f, 0.f, 0.f, 0.f};

  for (int k0 = 0; k0 < K; k0 += 32) {
    GLDS(Ap0 + k0, Aw0);
    GLDS(Ap1 + k0, Aw1);
    GLDS(Bp0 + k0, Bw0);
    GLDS(Bp1 + k0, Bw1);
    __syncthreads();
    b8 af[4], bf[4];
#pragma unroll
    for (int i = 0; i < 4; i++)
      af[i] = *(const b8*)&Asp[(wr * 64 + i * 16 + l16) * 32 + q * 8];
#pragma unroll
    for (int j = 0; j < 4; j++)
      bf[j] = *(const b8*)&Bsp[(wc * 64 + j * 16 + l16) * 32 + q * 8];
#pragma unroll
    for (int i = 0; i < 4; i++)
#pragma unroll
      for (int j = 0; j < 4; j++)
        acc[i][j] = __builtin_amdgcn_mfma_f32_16x16x32_bf16(af[i], bf[j], acc[i][j], 0, 0, 0);
    __syncthreads();
  }
  if (EPI == 4) {
#pragma unroll
    for (int j = 0; j < 4; j++) {
      int n = n0 + wc * 64 + j * 16 + l16;
#pragma unroll
      for (int i = 0; i < 4; i++) {
        int m = m0 + wr * 64 + i * 16 + (q << 2);
        __hip_bfloat16 t4[4];
#pragma unroll
        for (int r = 0; r < 4; r++) t4[r] = __float2bfloat16(acc[i][j][r]);
        long bidx = (long)(m >> 8) * sC + (long)n * cL + (m & 255);
        *(uint2*)&((__hip_bfloat16*)Cv)[bidx] = *(uint2*)t4;
      }
    }
    return;
  }
  long cz = (long)(z >> czdiv) * sC;
#pragma unroll
  for (int j = 0; j < 4; j++) {
    int n = n0 + wc * 64 + j * 16 + l16;
    float bv = BIAS ? bias[n] : 0.f;
#pragma unroll
    for (int i = 0; i < 4; i++) {
#pragma unroll
      for (int r = 0; r < 4; r++) {
        int m = m0 + wr * 64 + i * 16 + q * 4 + r;
        long idx = cz + (long)m * ldc + n;
        float v = acc[i][j][r] + bv;
        if (EPI == 0) {
          if (RELU) v = fmaxf(v, 0.f);
          if (OBF)
            ((__hip_bfloat16*)Cv)[idx] = __float2bfloat16(v);
          else
            ((float*)Cv)[idx] = v;
        } else {
          // EPI==2: v = Hout = relu(acc+bias); h = bf16 H (auxb);
          // H' = h + sig(h)*(Hout - h); write bf16 always, f32 only if auxf.
          v = fmaxf(v, 0.f);
          float h = __bfloat162float(auxb[idx]);
          float g = sigf(h);
          float o = h + g * (v - h);
          auxb[idx] = __float2bfloat16(o);
          if (auxf) auxf[idx] = o;
        }
      }
    }
  }
}

// ======== dual adjacency GEMM: Isem/Ilat share BT; fused I_com epilogue ========
// XCD swizzle over full 3D id (768 blocks): each XCD owns 8 consecutive batches.
__global__ __launch_bounds__(256, 2) void bgemm_dual(
    const __hip_bfloat16* __restrict__ A1g, const __hip_bfloat16* __restrict__ A2g,
    const __hip_bfloat16* __restrict__ BTg, float* __restrict__ IsemF,
    __hip_bfloat16* __restrict__ Icb, const float* __restrict__ bias,
    int write_isem) {
  __shared__ __hip_bfloat16 A1sp[128 * 32];
  __shared__ __hip_bfloat16 A2sp[128 * 32];
  __shared__ __hip_bfloat16 Bsp[128 * 32];
  int id = (blockIdx.z * 2 + blockIdx.y) * 6 + blockIdx.x;  // 768 total
  id = (id & 7) * 96 + (id >> 3);
  int bx = id % 6, t = id / 6;
  int by = t & 1, z = t >> 1;
  const __hip_bfloat16* A1 = A1g + (long)z * cLL;
  const __hip_bfloat16* A2 = A2g + (long)z * cLL;
  const __hip_bfloat16* BT = BTg + (long)z * cLD;
  int tid = threadIdx.x;
  int lane = tid & 63, w = tid >> 6;
  int wr = w >> 1, wc = w & 1;
  int l16 = lane & 15, q = lane >> 4;
  int m0 = by << 7, n0 = bx << 7;

  int fm = tid >> 2, fq = tid & 3;
  const __hip_bfloat16* A1p0 = A1 + (long)(m0 + fm) * cL + fq * 8;
  const __hip_bfloat16* A1p1 = A1p0 + 64L * cL;
  const __hip_bfloat16* A2p0 = A2 + (long)(m0 + fm) * cL + fq * 8;
  const __hip_bfloat16* A2p1 = A2p0 + 64L * cL;
  const __hip_bfloat16* Bp0 = BT + (long)(n0 + fm) * cL + fq * 8;
  const __hip_bfloat16* Bp1 = Bp0 + 64L * cL;
  char* w10 = (char*)A1sp + (w << 10);
  char* w11 = (char*)A1sp + 4096 + (w << 10);
  char* w20 = (char*)A2sp + (w << 10);
  char* w21 = (char*)A2sp + 4096 + (w << 10);
  char* wb0 = (char*)Bsp + (w << 10);
  char* wb1 = (char*)Bsp + 4096 + (w << 10);

  f4 ac1[4][4], ac2[4][4];
#pragma unroll
  for (int i = 0; i < 4; i++)
#pragma unroll
    for (int j = 0; j < 4; j++) {
      ac1[i][j] = (f4){0.f, 0.f, 0.f, 0.f};
      ac2[i][j] = (f4){0.f, 0.f, 0.f, 0.f};
    }

  for (int k0 = 0; k0 < cL; k0 += 32) {
    GLDS(A1p0 + k0, w10);
    GLDS(A1p1 + k0, w11);
    GLDS(A2p0 + k0, w20);
    GLDS(A2p1 + k0, w21);
    GLDS(Bp0 + k0, wb0);
    GLDS(Bp1 + k0, wb1);
    __syncthreads();
    b8 a1f[4], a2f[4], bf[4];
#pragma unroll
    for (int i = 0; i < 4; i++) {
      a1f[i] = *(const b8*)&A1sp[(wr * 64 + i * 16 + l16) * 32 + q * 8];
      a2f[i] = *(const b8*)&A2sp[(wr * 64 + i * 16 + l16) * 32 + q * 8];
    }
#pragma unroll
    for (int j = 0; j < 4; j++)
      bf[j] = *(const b8*)&Bsp[(wc * 64 + j * 16 + l16) * 32 + q * 8];
#pragma unroll
    for (int i = 0; i < 4; i++)
#pragma unroll
      for (int j = 0; j < 4; j++) {
        ac1[i][j] = __builtin_amdgcn_mfma_f32_16x16x32_bf16(a1f[i], bf[j], ac1[i][j], 0, 0, 0);
        ac2[i][j] = __builtin_amdgcn_mfma_f32_16x16x32_bf16(a2f[i], bf[j], ac2[i][j], 0, 0, 0);
      }
    __syncthreads();
  }
  long cz = (long)z * cLD;
#pragma unroll
  for (int j = 0; j < 4; j++) {
    int n = n0 + wc * 64 + j * 16 + l16;
    float bv = bias[n];
#pragma unroll
    for (int i = 0; i < 4; i++) {
#pragma unroll
      for (int r = 0; r < 4; r++) {
        int m = m0 + wr * 64 + i * 16 + q * 4 + r;
        long idx = cz + (long)m * cD + n;
        float is = ac1[i][j][r] + bv;
        float il = ac2[i][j][r] + bv;
        float g = 0.5f * sigf(il);
        Icb[idx] = __float2bfloat16(is + g * (il - is));
        if (write_isem) IsemF[idx] = is;
      }
    }
  }
}

// ============ fused QK^T + mask(+dep) + row-softmax -> adjacency (bf16) ============
// Wave-owns-rows restructure: each wave handles 16 q-rows x all 256 cols
// (16 j-frags of 16x16x32), so row-softmax is WAVE-LOCAL (j-fold + 16-lane
// shfl_xor) — zero softmax barriers. K staged per 96-col chunk into padded LDS
// [256][104] (row = 13x16B chunks, 13th = pad dummy; bank stride 52 words,
// gcd(52,32)=4 -> 2 lanes/bank = conflict-free). Q read direct global->reg.
// 2 barriers per chunk x 8 chunks. Work remap: 4 m-blocks of a batch land on
// one XCD (id&7 selects XCD for consecutive hw ids) for K L2-locality.
// W<256: adj_ag (8 heads, cols [0|768)); W>=256: adj_lat (cols [1536|2304)).
__global__ __launch_bounds__(256, 2) void k_qkadj2(
    const __hip_bfloat16* __restrict__ qkb, const float* __restrict__ src_mask,
    const int* __restrict__ headv, const float* __restrict__ df,
    __hip_bfloat16* __restrict__ outAag, __hip_bfloat16* __restrict__ outAlat) {
  __shared__ __hip_bfloat16 Ks[256 * 104];  // 52 KB padded K chunk
  int id = (blockIdx.z * gridDim.y + blockIdx.y) * gridDim.x + blockIdx.x;  // 512
  int W = (id & 7) * 64 + (id >> 3);  // XCD-grouped work id (bijective)
  const bool lat = W >= 256;
  int rem = W & 255;
  const int b = rem >> 2, m0 = (rem & 3) << 6;
  const int QOFF = lat ? 1536 : 0;
  const int KOFF = lat ? 2304 : 768;
  const float scale = lat ? (1.f / sqrtf(768.f)) : (1.f / (sqrtf(96.f) + 1e-9f));
  const int tid = threadIdx.x, lane = tid & 63, w = tid >> 6;
  const int l16 = lane & 15, q = lane >> 4;
  const long rowbase = (long)b * cL;
  // Q: direct global, wave w owns rows m0+w*16..+16 (row = l16, k-off = q*8)
  const __hip_bfloat16* Qbase =
      qkb + (rowbase + m0 + w * 16 + l16) * 3072 + QOFF + q * 8;
  // K staging: 3328 padded 16B chunks; chunk ci -> row ci/13, col16 ci%13
  const __hip_bfloat16* Kg = qkb + rowbase * 3072 + KOFF;
  int kgo[13];
#pragma unroll
  for (int u = 0; u < 13; u++) {
    int ci = u * 256 + tid;
    int row = ci / 13, c16 = ci % 13;
    if (c16 == 12) c16 = 0;  // pad chunk: load dummy (never read)
    kgo[u] = row * 3072 + c16 * 8;
  }
  // col mask (col = j*16 + l16) — needed per-chunk for ag
  float smj[16];
#pragma unroll
  for (int j = 0; j < 16; j++) {
    int col = j * 16 + l16;
    smj[j] = (col == 0) ? 1.f : src_mask[b * cL + col];
  }

  f4 sa[16], aag[16];
#pragma unroll
  for (int j = 0; j < 16; j++) {
    sa[j] = (f4){0.f, 0.f, 0.f, 0.f};
    aag[j] = (f4){0.f, 0.f, 0.f, 0.f};
  }

  for (int c = 0; c < 8; c++) {
    const int hk = c * 96;
    if (c) __syncthreads();  // previous chunk's LDS reads complete
#pragma unroll
    for (int u = 0; u < 13; u++)
      GLDS(Kg + kgo[u] + hk, (char*)Ks + (u * 256 + w * 64) * 16);
    __syncthreads();  // staged K visible (drains vmcnt)
    if (!lat) {
#pragma unroll
      for (int j = 0; j < 16; j++) sa[j] = (f4){0.f, 0.f, 0.f, 0.f};
    }
#pragma unroll
    for (int s = 0; s < 3; s++) {
      b8 af = *(const b8*)(Qbase + hk + s * 32);
#pragma unroll
      for (int j = 0; j < 16; j++) {
        b8 bf = *(const b8*)&Ks[(j * 16 + l16) * 104 + s * 32 + q * 8];
        sa[j] = __builtin_amdgcn_mfma_f32_16x16x32_bf16(af, bf, sa[j], 0, 0, 0);
      }
    }
    if (!lat) {
      // per-head softmax, wave-local (rows r live in 16-lane l16 groups)
      float rm[4] = {-1e30f, -1e30f, -1e30f, -1e30f};
#pragma unroll
      for (int j = 0; j < 16; j++)
#pragma unroll
        for (int r = 0; r < 4; r++) {
          float v = (smj[j] == 0.f) ? -1e9f : sa[j][r] * scale;
          sa[j][r] = v;
          rm[r] = fmaxf(rm[r], v);
        }
#pragma unroll
      for (int r = 0; r < 4; r++)
#pragma unroll
        for (int o = 1; o < 16; o <<= 1) rm[r] = fmaxf(rm[r], __shfl_xor(rm[r], o, 64));
      float sum[4] = {0.f, 0.f, 0.f, 0.f};
#pragma unroll
      for (int j = 0; j < 16; j++)
#pragma unroll
        for (int r = 0; r < 4; r++) {
          float e = expf(sa[j][r] - rm[r]);
          sa[j][r] = e;
          sum[r] += e;
        }
#pragma unroll
      for (int r = 0; r < 4; r++) {
#pragma unroll
        for (int o = 1; o < 16; o <<= 1) sum[r] += __shfl_xor(sum[r], o, 64);
        sum[r] = 1.f / sum[r];
      }
#pragma unroll
      for (int j = 0; j < 16; j++)
#pragma unroll
        for (int r = 0; r < 4; r++) aag[j][r] += sa[j][r] * sum[r];
    }
  }

  float inv[4];
  if (lat) {
    // dep metadata loaded late (short live ranges)
    int hcol[16];
    float dfc[16];
#pragma unroll
    for (int j = 0; j < 16; j++) {
      int col = j * 16 + l16;
      hcol[j] = (col >= 1) ? headv[b * cL + col - 1] : -1;
      dfc[j] = (col >= 1) ? df[b * cL + col - 1] : 0.f;
    }
    int hrow_[4];
    float dfr_[4];
#pragma unroll
    for (int r = 0; r < 4; r++) {
      int grow = m0 + w * 16 + q * 4 + r;
      hrow_[r] = (grow >= 1) ? headv[b * cL + grow - 1] : -1;
      dfr_[r] = (grow >= 1) ? df[b * cL + grow - 1] : 0.f;
    }
    float rm[4] = {-1e30f, -1e30f, -1e30f, -1e30f};
#pragma unroll
    for (int j = 0; j < 16; j++) {
      int col = j * 16 + l16;
#pragma unroll
      for (int r = 0; r < 4; r++) {
        int grow = m0 + w * 16 + q * 4 + r;
        float dep = 1.f;
        if (hcol[j] == grow) dep = dfc[j];
        if (col == hrow_[r]) dep = dfr_[r];
        float v = sa[j][r] * scale + dep + (1.f - smj[j]) * -10000.f;
        sa[j][r] = v;
        rm[r] = fmaxf(rm[r], v);
      }
    }
#pragma unroll
    for (int r = 0; r < 4; r++)
#pragma unroll
      for (int o = 1; o < 16; o <<= 1) rm[r] = fmaxf(rm[r], __shfl_xor(rm[r], o, 64));
    float sum[4] = {0.f, 0.f, 0.f, 0.f};
#pragma unroll
    for (int j = 0; j < 16; j++)
#pragma unroll
      for (int r = 0; r < 4; r++) {
        float e = expf(sa[j][r] - rm[r]);
        sa[j][r] = e;
        sum[r] += e;
      }
#pragma unroll
    for (int r = 0; r < 4; r++) {
#pragma unroll
      for (int o = 1; o < 16; o <<= 1) sum[r] += __shfl_xor(sum[r], o, 64);
      inv[r] = 1.f / sum[r];
    }
  }

  float smi_[4];
#pragma unroll
  for (int r = 0; r < 4; r++) {
    int grow = m0 + w * 16 + q * 4 + r;
    smi_[r] = (grow == 0) ? 1.f : src_mask[b * cL + grow];
  }
  __hip_bfloat16* outA = lat ? outAlat : outAag;
#pragma unroll
  for (int j = 0; j < 16; j++) {
    int col = j * 16 + l16;
#pragma unroll
    for (int r = 0; r < 4; r++) {
      int grow = m0 + w * 16 + q * 4 + r;
      float p = lat ? sa[j][r] * inv[r] : aag[j][r] * 0.125f;
      float v = (col == grow) ? 1.f : p;
      outA[((long)b * cL + grow) * cL + col] = __float2bfloat16(v * smi_[r]);
    }
  }
}

// -------- 7 weight convert+transpose + bias-concat (z==7) in one dispatch --------
__global__ void k_wconv7(const float* __restrict__ s0, const float* __restrict__ s1,
                         const float* __restrict__ s2, const float* __restrict__ s3,
                         const float* __restrict__ s4, const float* __restrict__ s5,
                         const float* __restrict__ s6, __hip_bfloat16* __restrict__ dst,
                         const float* __restrict__ ba, const float* __restrict__ bb,
                         const float* __restrict__ bc, const float* __restrict__ bd,
                         float* __restrict__ catb) {
  if (blockIdx.z == 7) {
    if (blockIdx.y != 0 || blockIdx.x >= 12) return;
    int tid = threadIdx.y * 32 + threadIdx.x;
    int i = blockIdx.x * 256 + tid;
    float v = (i < 768) ? ba[i] : (i < 1536) ? bb[i - 768]
              : (i < 2304) ? bc[i - 1536] : bd[i - 2304];
    catb[i] = v;
    return;
  }
  const float* srcs[7] = {s0, s1, s2, s3, s4, s5, s6};
  const float* src = srcs[blockIdx.z];
  __hip_bfloat16* d = dst + (long)blockIdx.z * cD * cD;
  __shared__ float t[32][33];
  int k0 = blockIdx.x * 32, n0 = blockIdx.y * 32;
  int tx = threadIdx.x, ty = threadIdx.y;
#pragma unroll
  for (int i = 0; i < 32; i += 8) t[ty + i][tx] = src[(long)(k0 + ty + i) * cD + n0 + tx];
  __syncthreads();
#pragma unroll
  for (int i = 0; i < 32; i += 8)
    d[(long)(n0 + ty + i) * cD + k0 + tx] = __float2bfloat16(t[tx][ty + i]);
}

// -------- embedding + layernorm + root dot, wave-per-row (bf16-only H out) --------
__global__ __launch_bounds__(256) void k_gcnin(
    const int* __restrict__ tbi, const int* __restrict__ bsi,
    const float* __restrict__ tok, const float* __restrict__ seg,
    const float* __restrict__ ln_a, const float* __restrict__ ln_b,
    const float* __restrict__ root_w, __hip_bfloat16* __restrict__ gib,
    float* __restrict__ x64, float* __restrict__ e1) {
  int wave = threadIdx.x >> 6, lane = threadIdx.x & 63;
  long bl = (long)blockIdx.x * 4 + wave;
  int t = tbi[bl], s = bsi[bl];
  const float* tr = tok + (long)t * cD;
  const float* sr = seg + (long)s * cD;
  float x[12];
  float ls = 0.f;
#pragma unroll
  for (int c = 0; c < 12; c++) {
    int d = lane + (c << 6);
    x[c] = tr[d] + sr[d];
    ls += x[c];
  }
  if ((bl & 255) == 0) {
#pragma unroll
    for (int c = 0; c < 12; c++) x64[(bl >> 8) * cD + lane + (c << 6)] = x[c];
  }
  float mean = wsum_all(ls) * (1.f / 768.f);
  float lv = 0.f;
#pragma unroll
  for (int c = 0; c < 12; c++) { float d2 = x[c] - mean; lv += d2 * d2; }
  float var = wsum_all(lv) * (1.f / 767.f);
  float inv = 1.f / (sqrtf(var) + 1e-6f);
  float rdot = 0.f;
#pragma unroll
  for (int c = 0; c < 12; c++) {
    int d = lane + (c << 6);
    float v = ln_a[d] * (x[c] - mean) * inv + ln_b[d];
    gib[bl * cD + d] = __float2bfloat16(v);
    rdot += v * root_w[d];
  }
  float tot = wsum_all(rdot);
  if (lane == 0) e1[bl] = tot;
}

// ---------------- pooled GEMV partials ----------------
__global__ __launch_bounds__(256) void k_pool1(
    const float* __restrict__ x64, const float* __restrict__ pw,
    float* __restrict__ pacc) {
  __shared__ float pws[48][256];
  __shared__ float xs[16][48];
  int i0 = blockIdx.x * 48, j0 = blockIdx.y * 256, b0 = blockIdx.z * 16;
  for (int r = 0; r < 48; r++) pws[r][threadIdx.x] = pw[(long)(i0 + r) * cD + j0 + threadIdx.x];
  for (int idx = threadIdx.x; idx < 16 * 48; idx += 256)
    xs[idx / 48][idx % 48] = x64[(long)(b0 + idx / 48) * cD + i0 + idx % 48];
  __syncthreads();
  int j = threadIdx.x;
  for (int b = 0; b < 16; b++) {
    float acc = 0.f;
#pragma unroll 8
    for (int i = 0; i < 48; i++) acc += xs[b][i] * pws[i][j];
    atomicAdd(&pacc[(long)(b0 + b) * cD + j0 + j], acc);
  }
}

// ---------------- dep LUT ----------------
__global__ __launch_bounds__(256) void k_s45(
    const float* __restrict__ dep_emb, const float* __restrict__ fc1w,
    const float* __restrict__ fc1b, const float* __restrict__ fc2w,
    const float* __restrict__ fc2b, float* __restrict__ s45) {
  int t = blockIdx.x;
  __shared__ float e[300];
  for (int i = threadIdx.x; i < 300; i += 256) e[i] = dep_emb[t * 300 + i];
  __syncthreads();
  int j = threadIdx.x;
  float h = fc1b[j];
  for (int i = 0; i < 300; i++) h += e[i] * fc1w[i * 256 + j];
  h = fmaxf(h, 0.f);
  float tot = blockSum(h * fc2w[j]);
  if (threadIdx.x == 0) s45[t] = tot + fc2b[0];
}

__global__ __launch_bounds__(256) void k_depfeat(
    const int* __restrict__ ori, const float* __restrict__ src_mask,
    const float* __restrict__ s45, float* __restrict__ dep_feat) {
  int b = blockIdx.x, l = threadIdx.x;
  float smv = (l == 0) ? 1.f : src_mask[b * cL + l];
  float sc = s45[ori[b * cL + l]] * smv + (1.f - smv) * (-1e30f);
  float mx = blockMax(sc);
  float ex = expf(sc - mx);
  float sum = blockSum(ex);
  dep_feat[b * cL + l] = ex / sum;
}

// ---------------- merged wave-per-row dots: y==0 sraw=Isem.hlsum, y==1 e2=H.vlin ----------------
__global__ __launch_bounds__(256) void k_rowdot2(
    const float* __restrict__ Isem, const float* __restrict__ hlsum,
    const float* __restrict__ gcnH, const float* __restrict__ vlin,
    float* __restrict__ sraw, float* __restrict__ e2) {
  int r = blockIdx.x * 4 + (threadIdx.x >> 6);
  int lane = threadIdx.x & 63;
  bool z = blockIdx.y != 0;
  const float4* row = (const float4*)((z ? gcnH : Isem) + (long)r * cD);
  const float4* wp = z ? (const float4*)vlin
                       : (const float4*)(hlsum + (long)(r >> 8) * cD);
  float s = 0.f;
#pragma unroll
  for (int c = 0; c < 3; c++) {
    int idx = c * 64 + lane;
    float4 a = row[idx], b = wp[idx];
    s += a.x * b.x + a.y * b.y + a.z * b.z + a.w * b.w;
  }
  s = wsum(s);
  if (lane == 0) (z ? e2 : sraw)[r] = s;
}

// -------- merged per-batch tail reductions: attn weights + root loss + lex loss --------
__global__ __launch_bounds__(256) void k_tailred(
    const float* __restrict__ sraw, const float* __restrict__ e1,
    const float* __restrict__ e2, const float* __restrict__ src_mask,
    const float* __restrict__ aspect_mask, const float* __restrict__ lex,
    float* __restrict__ wgt, float* __restrict__ asum,
    float* __restrict__ out_root, float* __restrict__ out_lex) {
  int b = blockIdx.x, l = threadIdx.x;
  float smv = (l == 0) ? 1.f : src_mask[b * cL + l];
  float am = aspect_mask[b * cL + l];
  // attn weights + asum
  float s = sraw[b * cL + l] * smv * 0.001f;
  float mx = blockMax(s);
  float ex = expf(s - mx);
  float sum = blockSum(ex);
  wgt[b * cL + l] = ex / sum;
  float a = blockSum(am);
  if (l == 0) asum[b] = a;
  // root loss
  float sc = e1[b * cL + l] * smv + (1.f - smv) * (-1e30f);
  float mx2 = blockMax(sc);
  float ex2 = expf(sc - mx2);
  float sum2 = blockSum(ex2);
  float tot = blockSum((ex2 / sum2) * am);
  if (l == 0) atomicAdd(out_root, -logf(tot + 1e-9f) * (1.f / 64.f));
  // lexicon loss
  float e = e2[b * cL + l];
  float mx3 = blockMax(e);
  float ex3 = expf(e - mx3);
  float sum3 = blockSum(ex3);
  float mult = (l == 0) ? 0.f : src_mask[b * cL + l];
  float lw = ex3 / sum3 * 50.f * mult;
  float d2 = lw - lex[b * cL + l];
  float t3 = blockSum(d2 * d2);
  if (l == 0) atomicAdd(out_lex, t3 * (1.f / (64.f * 256.f)));
}

// ---------------- hlsum partials ----------------
__global__ __launch_bounds__(256) void k_hl(
    const float* __restrict__ H, const float* __restrict__ src_mask,
    float* __restrict__ hlsum) {
  int b = blockIdx.z, d = (blockIdx.y << 8) + threadIdx.x, l0 = blockIdx.x * 32;
  float acc = 0.f;
  for (int l = l0; l < l0 + 32; l++) {
    float smv = (l == 0) ? 1.f : src_mask[b * cL + l];
    acc += H[((long)b * cL + l) * cD + d] * smv;
  }
  atomicAdd(&hlsum[(long)b * cD + d], acc);
}

// ---------------- fused outputs+sempool partials ----------------
__global__ __launch_bounds__(256) void k_wsum(
    const float* __restrict__ Isem, const float* __restrict__ wgt,
    const float* __restrict__ am, float* __restrict__ outputs,
    float* __restrict__ sempool) {
  int b = blockIdx.z, d = (blockIdx.y << 8) + threadIdx.x, l0 = blockIdx.x * 32;
  float accO = 0.f, accS = 0.f;
  for (int l = l0; l < l0 + 32; l++) {
    float v = Isem[((long)b * cL + l) * cD + d];
    accO += wgt[b * cL + l] * v;
    accS += am[b * cL + l] * v;
  }
  atomicAdd(&outputs[(long)b * cD + d], accO);
  atomicAdd(&sempool[(long)b * cD + d], accS);
}

// ---------------- logits (pooled = tanh(pacc+pb) folded in) ----------------
__global__ __launch_bounds__(256) void k_logits(
    const float* __restrict__ outputs, const float* __restrict__ sempool,
    const float* __restrict__ pacc, const float* __restrict__ pb,
    const float* __restrict__ asum, const float* __restrict__ cw,
    const float* __restrict__ cb, float* __restrict__ out) {
  int b = blockIdx.x;
  float inv = 1.f / (asum[b] + 1e-9f);
  float a0 = 0.f, a1 = 0.f, a2 = 0.f;
  for (int i = threadIdx.x; i < 3 * cD; i += 256) {
    float f;
    if (i < cD)
      f = outputs[(long)b * cD + i];
    else if (i < 2 * cD)
      f = sempool[(long)b * cD + i - cD] * inv;
    else
      f = tanhf(pacc[(long)b * cD + i - 2 * cD] + pb[i - 2 * cD]);
    a0 += f * cw[i * 3 + 0];
    a1 += f * cw[i * 3 + 1];
    a2 += f * cw[i * 3 + 2];
  }
  a0 = blockSum(a0);
  a1 = blockSum(a1);
  a2 = blockSum(a2);
  if (threadIdx.x == 0) {
    out[b * 3 + 0] = a0 + cb[0];
    out[b * 3 + 1] = a1 + cb[1];
    out[b * 3 + 2] = a2 + cb[2];
  }
}

extern "C" void kernel_launch(void* const* d_in, const int* in_sizes, int n_in,
                              void* d_out, int out_size, void* d_ws, size_t ws_size,
                              hipStream_t stream) {
  const int* tbi = (const int*)d_in[0];
  const int* bsi = (const int*)d_in[1];
  const float* src_mask = (const float*)d_in[3];
  const float* aspect_mask = (const float*)d_in[4];
  const float* lex = (const float*)d_in[5];
  const int* ori = (const int*)d_in[6];
  const int* head = (const int*)d_in[7];
  const float* tok_emb = (const float*)d_in[8];
  const float* seg_emb = (const float*)d_in[9];
  const float* pool_w = (const float*)d_in[10];
  const float* pool_b = (const float*)d_in[11];
  const float* ln_a = (const float*)d_in[12];
  const float* ln_b = (const float*)d_in[13];
  const float* dep_emb = (const float*)d_in[14];
  const float* fc1_w = (const float*)d_in[15];
  const float* fc1_b = (const float*)d_in[16];
  const float* fc2_w = (const float*)d_in[17];
  const float* fc2_b = (const float*)d_in[18];
  const float* aq_w = (const float*)d_in[19];
  const float* aq_b = (const float*)d_in[20];
  const float* ak_w = (const float*)d_in[21];
  const float* ak_b = (const float*)d_in[22];
  const float* lq_w = (const float*)d_in[23];
  const float* lq_b = (const float*)d_in[24];
  const float* lk_w = (const float*)d_in[25];
  const float* lk_b = (const float*)d_in[26];
  const float* root_w = (const float*)d_in[27];
  const float* gcn_w = (const float*)d_in[28];
  const float* gcn_b = (const float*)d_in[29];
  const float* fc3_w = (const float*)d_in[30];
  const float* fc3_b = (const float*)d_in[31];
  const float* cls_w = (const float*)d_in[32];
  const float* cls_b = (const float*)d_in[33];
  const float* vlin_w = (const float*)d_in[34];

  float* out = (float*)d_out;
  float* ws = (float*)d_ws;
  // fp32 region
  float* gcnH = ws;            // BLD (H2 f32, written by layer-1 fc3)
  float* Isem = gcnH + BLD;    // BLD
  float* depfeat = Isem + BLD;         // B*L
  float* s45 = depfeat + cB * cL;      // 64
  float* pooled = s45 + 64;            // B*D (unused)
  float* x64 = pooled + cB * cD;       // B*D
  float* hlsum = x64 + cB * cD;        // B*D  --- zeroed region start
  float* outputs = hlsum + cB * cD;    // B*D
  float* sempool = outputs + cB * cD;  // B*D
  float* pacc = sempool + cB * cD;     // B*D  --- zeroed region end
  float* e1 = pacc + cB * cD;          // B*L
  float* e2 = e1 + cB * cL;            // B*L
  float* sraw = e2 + cB * cL;          // B*L
  float* wgt = sraw + cB * cL;         // B*L
  float* asum = wgt + cB * cL;         // 64
  float* catb = asum + 64;             // 3072
  // bf16 region
  __hip_bfloat16* gib = (__hip_bfloat16*)(catb + 3072);  // BLD (H state, bf16)
  __hip_bfloat16* qkb = gib + BLD;             // 4*BLD (q|k|q2|k2, ldc=3072)
  __hip_bfloat16* scores = qkb + 4 * BLD;      // (unused, kept for layout)
  __hip_bfloat16* adjag_b = scores + 8 * BLL;  // BLL
  __hip_bfloat16* adjlat_b = adjag_b + BLL;    // BLL
  __hip_bfloat16* wbt = adjlat_b + BLL;        // 7*D*D
  // aliases
  __hip_bfloat16* HWbT = qkb + BLD;     // BLD (HW^T, written directly by EPI=4)
  __hip_bfloat16* Icb = qkb + 2 * BLD;  // BLD

  hipMemsetAsync((char*)d_out + 192 * sizeof(float), 0, 2 * sizeof(float), stream);
  hipMemsetAsync(hlsum, 0, 4 * cB * cD * sizeof(float), stream);

  // ---- prologue ----
  k_gcnin<<<cB * cL / 4, 256, 0, stream>>>(tbi, bsi, tok_emb, seg_emb, ln_a, ln_b,
                                           root_w, gib, x64, e1);
  k_s45<<<45, 256, 0, stream>>>(dep_emb, fc1_w, fc1_b, fc2_w, fc2_b, s45);
  k_depfeat<<<cB, 256, 0, stream>>>(ori, src_mask, s45, depfeat);
  k_pool1<<<dim3(16, 3, 4), 256, 0, stream>>>(x64, pool_w, pacc);
  k_wconv7<<<dim3(24, 24, 8), dim3(32, 8), 0, stream>>>(
      aq_w, ak_w, lq_w, lk_w, gcn_w, gcn_w + (long)cD * cD, fc3_w, wbt,
      aq_b, ak_b, lq_b, lk_b, catb);

  const long DD = (long)cD * cD;
  const long LD = cLD;

  // ---- fused 4-way projection: qkb = gib @ [aq|ak|lq|lk] + catb (XCD-swizzled) ----
  bgemm<1, 0, 1, 0, 1><<<dim3(24, 128, 1), 256, 0, stream>>>(
      gib, wbt, qkb, catb, nullptr, nullptr, cD, cD, cD, 3072,
      0, 0, 0, 0, 0, 0, 0, 0);

  // ---- fused adjacency builders (one dispatch, wave-local softmax) ----
  k_qkadj2<<<dim3(4, cB, 2), 256, 0, stream>>>(qkb, src_mask, head, depfeat,
                                               adjag_b, adjlat_b);

  // ---- GCN loop ----
  for (int layer = 0; layer < 2; layer++) {
    const float* bb = gcn_b + (long)layer * cD;
    // HW^T = (H @ W)^T written directly (EPI=4), layout (b, d, l)
    bgemm<1, 0, 0, 4, 1><<<dim3(6, 128, 1), 256, 0, stream>>>(
        gib, wbt + (4 + layer) * DD, HWbT, nullptr, nullptr, nullptr,
        cD, cD, cD, cD, 0, 0, 0, 0, 0, 0, LD, 0);
    // dual adjacency GEMM + fused I_com epilogue (writes Isem f32 on last layer)
    bgemm_dual<<<dim3(6, 2, cB), 256, 0, stream>>>(
        adjag_b, adjlat_b, HWbT, Isem, Icb, bb, layer == 1 ? 1 : 0);
    // fc3 GEMM + H-gate epilogue on bf16 H (gib); f32 H only on last layer (tail)
    bgemm<0, 1, 1, 2, 1><<<dim3(6, 128, 1), 256, 0, stream>>>(
        Icb, wbt + 6 * DD, nullptr, fc3_b, layer == 1 ? gcnH : nullptr, gib,
        cD, cD, cD, cD, 0, 0, 0, 0, 0, 0, 0, 0);
  }

  // ---- tail ----
  k_hl<<<dim3(8, 3, cB), 256, 0, stream>>>(gcnH, src_mask, hlsum);
  k_rowdot2<<<dim3(cB * cL / 4, 2), 256, 0, stream>>>(Isem, hlsum, gcnH, vlin_w,
                                                      sraw, e2);
  k_tailred<<<cB, 256, 0, stream>>>(sraw, e1, e2, src_mask, aspect_mask, lex,
                                    wgt, asum, out + 192, out + 193);
  k_wsum<<<dim3(8, 3, cB), 256, 0, stream>>>(Isem, wgt, aspect_mask, outputs, sempool);
  k_logits<<<cB, 256, 0, stream>>>(outputs, sempool, pacc, pool_b, asum,
                                   cls_w, cls_b, out);
}

// Round 7
// 727.576 us; speedup vs baseline: 1.1564x; 1.1564x over previous
//
#include <hip/hip_runtime.h>
#include <hip/hip_bf16.h>
#include <math.h>

#define DI __device__ __forceinline__

constexpr int cB = 64, cL = 256, cD = 768;
constexpr long BLD = (long)cB * cL * cD;   // 12,582,912
constexpr long BLL = (long)cB * cL * cL;   //  4,194,304
constexpr long cLL = (long)cL * cL;
constexpr long cLD = (long)cL * cD;

typedef __attribute__((ext_vector_type(8))) short b8;
typedef __attribute__((ext_vector_type(4))) float f4;

// async global->LDS, 16B per lane, dest = wave-uniform base + lane*16 (linear)
#define GLDS(g, l)                                                    \
  __builtin_amdgcn_global_load_lds(                                   \
      (const __attribute__((address_space(1))) void*)(g),             \
      (__attribute__((address_space(3))) void*)(l), 16, 0, 0)

#define SCB __builtin_amdgcn_sched_barrier(0)
// raw barrier (no vmcnt drain)
DI void rbar() { SCB; __builtin_amdgcn_s_barrier(); SCB; }
// LDS-visibility barrier: drain lgkmcnt only (ds_writes visible), no vmcnt drain
DI void lbar() {
  asm volatile("s_waitcnt lgkmcnt(0)" ::: "memory");
  SCB;
  __builtin_amdgcn_s_barrier();
  SCB;
}

// ---------------- reductions (wave64) ----------------
DI float wsum(float v) {
#pragma unroll
  for (int o = 32; o > 0; o >>= 1) v += __shfl_down(v, o, 64);
  return v;
}
DI float wsum_all(float v) {
#pragma unroll
  for (int m = 32; m > 0; m >>= 1) v += __shfl_xor(v, m, 64);
  return v;
}
DI float wmaxr(float v) {
#pragma unroll
  for (int o = 32; o > 0; o >>= 1) v = fmaxf(v, __shfl_down(v, o, 64));
  return v;
}
DI float blockSum(float v) {
  __shared__ float sh[4];
  v = wsum(v);
  __syncthreads();
  if ((threadIdx.x & 63) == 0) sh[threadIdx.x >> 6] = v;
  __syncthreads();
  return sh[0] + sh[1] + sh[2] + sh[3];
}
DI float blockMax(float v) {
  __shared__ float sh[4];
  v = wmaxr(v);
  __syncthreads();
  if ((threadIdx.x & 63) == 0) sh[threadIdx.x >> 6] = v;
  __syncthreads();
  return fmaxf(fmaxf(sh[0], sh[1]), fmaxf(sh[2], sh[3]));
}
DI float sigf(float x) { return 1.f / (1.f + expf(-x)); }

// ================= bf16 MFMA GEMM: C = A(MxK) @ BT(NxK)^T =================
// 128x128 tile, 4 waves, 4x4 of 16x16x32 frags/wave, BK=32.
// Staging via global_load_lds width=16; linear LDS [128][32] per tile.
// SWZ: XCD-contiguous tile remap (T1) — requires gridDim.x*gridDim.y % 8 == 0.
// EPI: 0=plain (OBF/RELU), 2=H-update (gate vs bf16 H in auxb; optional f32 out),
//      4=transposed bf16 write (per-256-row batch).
template <int OBF, int RELU, int BIAS, int EPI, int SWZ>
__global__ __launch_bounds__(256, 2) void bgemm(
    const __hip_bfloat16* __restrict__ A, const __hip_bfloat16* __restrict__ BT,
    void* __restrict__ Cv, const float* __restrict__ bias,
    float* __restrict__ auxf, __hip_bfloat16* __restrict__ auxb,
    int K, int lda, int ldb, int ldc,
    int zshift, int zmask, long sA1, long sA2, long sB1, long sB2, long sC,
    int czdiv) {
  __shared__ __hip_bfloat16 Asp[128 * 32];
  __shared__ __hip_bfloat16 Bsp[128 * 32];
  int bx = blockIdx.x, by = blockIdx.y;
  if (SWZ) {
    int gx = gridDim.x;
    int nb = gx * gridDim.y;
    int id = by * gx + bx;
    int cpx = nb >> 3;
    id = (id & 7) * cpx + (id >> 3);  // XCD k executes contiguous chunk k
    bx = id % gx;
    by = id / gx;
  }
  int z = blockIdx.z;
  A += (long)(z >> zshift) * sA1 + (long)(z & zmask) * sA2;
  BT += (long)(z >> zshift) * sB1 + (long)(z & zmask) * sB2;
  int tid = threadIdx.x;
  int lane = tid & 63, w = tid >> 6;
  int wr = w >> 1, wc = w & 1;
  int l16 = lane & 15, q = lane >> 4;
  int m0 = by << 7, n0 = bx << 7;

  int fm = tid >> 2, fq = tid & 3;
  const __hip_bfloat16* Ap0 = A + (long)(m0 + fm) * lda + fq * 8;
  const __hip_bfloat16* Ap1 = A + (long)(m0 + fm + 64) * lda + fq * 8;
  const __hip_bfloat16* Bp0 = BT + (long)(n0 + fm) * ldb + fq * 8;
  const __hip_bfloat16* Bp1 = BT + (long)(n0 + fm + 64) * ldb + fq * 8;
  char* Aw0 = (char*)Asp + (w << 10);
  char* Aw1 = (char*)Asp + 4096 + (w << 10);
  char* Bw0 = (char*)Bsp + (w << 10);
  char* Bw1 = (char*)Bsp + 4096 + (w << 10);

  f4 acc[4][4];
#pragma unroll
  for (int i = 0; i < 4; i++)
#pragma unroll
    for (int j = 0; j < 4; j++) acc[i][j] = (f4){0.f, 0.f, 0.f, 0.f};

  for (int k0 = 0; k0 < K; k0 += 32) {
    GLDS(Ap0 + k0, Aw0);
    GLDS(Ap1 + k0, Aw1);
    GLDS(Bp0 + k0, Bw0);
    GLDS(Bp1 + k0, Bw1);
    __syncthreads();
    b8 af[4], bf[4];
#pragma unroll
    for (int i = 0; i < 4; i++)
      af[i] = *(const b8*)&Asp[(wr * 64 + i * 16 + l16) * 32 + q * 8];
#pragma unroll
    for (int j = 0; j < 4; j++)
      bf[j] = *(const b8*)&Bsp[(wc * 64 + j * 16 + l16) * 32 + q * 8];
#pragma unroll
    for (int i = 0; i < 4; i++)
#pragma unroll
      for (int j = 0; j < 4; j++)
        acc[i][j] = __builtin_amdgcn_mfma_f32_16x16x32_bf16(af[i], bf[j], acc[i][j], 0, 0, 0);
    __syncthreads();
  }
  if (EPI == 4) {
#pragma unroll
    for (int j = 0; j < 4; j++) {
      int n = n0 + wc * 64 + j * 16 + l16;
#pragma unroll
      for (int i = 0; i < 4; i++) {
        int m = m0 + wr * 64 + i * 16 + (q << 2);
        __hip_bfloat16 t4[4];
#pragma unroll
        for (int r = 0; r < 4; r++) t4[r] = __float2bfloat16(acc[i][j][r]);
        long bidx = (long)(m >> 8) * sC + (long)n * cL + (m & 255);
        *(uint2*)&((__hip_bfloat16*)Cv)[bidx] = *(uint2*)t4;
      }
    }
    return;
  }
  long cz = (long)(z >> czdiv) * sC;
#pragma unroll
  for (int j = 0; j < 4; j++) {
    int n = n0 + wc * 64 + j * 16 + l16;
    float bv = BIAS ? bias[n] : 0.f;
#pragma unroll
    for (int i = 0; i < 4; i++) {
#pragma unroll
      for (int r = 0; r < 4; r++) {
        int m = m0 + wr * 64 + i * 16 + q * 4 + r;
        long idx = cz + (long)m * ldc + n;
        float v = acc[i][j][r] + bv;
        if (EPI == 0) {
          if (RELU) v = fmaxf(v, 0.f);
          if (OBF)
            ((__hip_bfloat16*)Cv)[idx] = __float2bfloat16(v);
          else
            ((float*)Cv)[idx] = v;
        } else {
          // EPI==2: v = Hout = relu(acc+bias); h = bf16 H (auxb);
          // H' = h + sig(h)*(Hout - h); write bf16 always, f32 only if auxf.
          v = fmaxf(v, 0.f);
          float h = __bfloat162float(auxb[idx]);
          float g = sigf(h);
          float o = h + g * (v - h);
          auxb[idx] = __float2bfloat16(o);
          if (auxf) auxf[idx] = o;
        }
      }
    }
  }
}

// ======== dual adjacency GEMM: Isem/Ilat share BT; fused I_com epilogue ========
// XCD swizzle over full 3D id (768 blocks): each XCD owns 8 consecutive batches.
__global__ __launch_bounds__(256, 2) void bgemm_dual(
    const __hip_bfloat16* __restrict__ A1g, const __hip_bfloat16* __restrict__ A2g,
    const __hip_bfloat16* __restrict__ BTg, float* __restrict__ IsemF,
    __hip_bfloat16* __restrict__ Icb, const float* __restrict__ bias,
    int write_isem) {
  __shared__ __hip_bfloat16 A1sp[128 * 32];
  __shared__ __hip_bfloat16 A2sp[128 * 32];
  __shared__ __hip_bfloat16 Bsp[128 * 32];
  int id = (blockIdx.z * 2 + blockIdx.y) * 6 + blockIdx.x;  // 768 total
  id = (id & 7) * 96 + (id >> 3);
  int bx = id % 6, t = id / 6;
  int by = t & 1, z = t >> 1;
  const __hip_bfloat16* A1 = A1g + (long)z * cLL;
  const __hip_bfloat16* A2 = A2g + (long)z * cLL;
  const __hip_bfloat16* BT = BTg + (long)z * cLD;
  int tid = threadIdx.x;
  int lane = tid & 63, w = tid >> 6;
  int wr = w >> 1, wc = w & 1;
  int l16 = lane & 15, q = lane >> 4;
  int m0 = by << 7, n0 = bx << 7;

  int fm = tid >> 2, fq = tid & 3;
  const __hip_bfloat16* A1p0 = A1 + (long)(m0 + fm) * cL + fq * 8;
  const __hip_bfloat16* A1p1 = A1p0 + 64L * cL;
  const __hip_bfloat16* A2p0 = A2 + (long)(m0 + fm) * cL + fq * 8;
  const __hip_bfloat16* A2p1 = A2p0 + 64L * cL;
  const __hip_bfloat16* Bp0 = BT + (long)(n0 + fm) * cL + fq * 8;
  const __hip_bfloat16* Bp1 = Bp0 + 64L * cL;
  char* w10 = (char*)A1sp + (w << 10);
  char* w11 = (char*)A1sp + 4096 + (w << 10);
  char* w20 = (char*)A2sp + (w << 10);
  char* w21 = (char*)A2sp + 4096 + (w << 10);
  char* wb0 = (char*)Bsp + (w << 10);
  char* wb1 = (char*)Bsp + 4096 + (w << 10);

  f4 ac1[4][4], ac2[4][4];
#pragma unroll
  for (int i = 0; i < 4; i++)
#pragma unroll
    for (int j = 0; j < 4; j++) {
      ac1[i][j] = (f4){0.f, 0.f, 0.f, 0.f};
      ac2[i][j] = (f4){0.f, 0.f, 0.f, 0.f};
    }

  for (int k0 = 0; k0 < cL; k0 += 32) {
    GLDS(A1p0 + k0, w10);
    GLDS(A1p1 + k0, w11);
    GLDS(A2p0 + k0, w20);
    GLDS(A2p1 + k0, w21);
    GLDS(Bp0 + k0, wb0);
    GLDS(Bp1 + k0, wb1);
    __syncthreads();
    b8 a1f[4], a2f[4], bf[4];
#pragma unroll
    for (int i = 0; i < 4; i++) {
      a1f[i] = *(const b8*)&A1sp[(wr * 64 + i * 16 + l16) * 32 + q * 8];
      a2f[i] = *(const b8*)&A2sp[(wr * 64 + i * 16 + l16) * 32 + q * 8];
    }
#pragma unroll
    for (int j = 0; j < 4; j++)
      bf[j] = *(const b8*)&Bsp[(wc * 64 + j * 16 + l16) * 32 + q * 8];
#pragma unroll
    for (int i = 0; i < 4; i++)
#pragma unroll
      for (int j = 0; j < 4; j++) {
        ac1[i][j] = __builtin_amdgcn_mfma_f32_16x16x32_bf16(a1f[i], bf[j], ac1[i][j], 0, 0, 0);
        ac2[i][j] = __builtin_amdgcn_mfma_f32_16x16x32_bf16(a2f[i], bf[j], ac2[i][j], 0, 0, 0);
      }
    __syncthreads();
  }
  long cz = (long)z * cLD;
#pragma unroll
  for (int j = 0; j < 4; j++) {
    int n = n0 + wc * 64 + j * 16 + l16;
    float bv = bias[n];
#pragma unroll
    for (int i = 0; i < 4; i++) {
#pragma unroll
      for (int r = 0; r < 4; r++) {
        int m = m0 + wr * 64 + i * 16 + q * 4 + r;
        long idx = cz + (long)m * cD + n;
        float is = ac1[i][j][r] + bv;
        float il = ac2[i][j][r] + bv;
        float g = 0.5f * sigf(il);
        Icb[idx] = __float2bfloat16(is + g * (il - is));
        if (write_isem) IsemF[idx] = is;
      }
    }
  }
}

// ============ fused QK^T + mask(+dep) + row-softmax -> adjacency (bf16) ============
// Column-split layout (4 waves over cols, sa[4][4] — no spill), with a
// double-buffered 24-step staging pipeline: counted vmcnt(5) + raw barriers,
// never vmcnt(0) mid-loop. Stage(s+2) issued right after the post-compute
// barrier, so each wait is for a stage two iterations old (latency hidden).
// ag (8 heads x 3 steps) and lat (24 steps) linearize to the same contiguous
// column walk s*32. Softmax uses red[] with lgkmcnt-only barriers (lbar) so
// the in-flight prefetch is never drained. XCD W-remap groups a batch's
// blocks on one XCD for K L2-locality.
__global__ __launch_bounds__(256, 2) void k_qkadj2(
    const __hip_bfloat16* __restrict__ qkb, const float* __restrict__ src_mask,
    const int* __restrict__ headv, const float* __restrict__ df,
    __hip_bfloat16* __restrict__ outAag, __hip_bfloat16* __restrict__ outAlat) {
  __shared__ __hip_bfloat16 Qs[2][64 * 32];   // 2 x 4 KB
  __shared__ __hip_bfloat16 Ks[2][256 * 32];  // 2 x 16 KB
  __shared__ float red[4][64];
  int id = (blockIdx.z * gridDim.y + blockIdx.y) * gridDim.x + blockIdx.x;  // 512
  int W = (id & 7) * 64 + (id >> 3);  // XCD-grouped work id (bijective)
  const bool lat = W >= 256;
  int rem = W & 255;
  const int b = rem >> 2, m0 = (rem & 3) << 6;
  const int QOFF = lat ? 1536 : 0;
  const int KOFF = lat ? 2304 : 768;
  const float scale = lat ? (1.f / sqrtf(768.f)) : (1.f / (sqrtf(96.f) + 1e-9f));
  const int tid = threadIdx.x, lane = tid & 63, w = tid >> 6;
  const int l16 = lane & 15, q = lane >> 4;
  const long rowbase = (long)b * cL;
  // staging sources: Q rows m0..m0+63 x 32 cols; K rows 0..255 x 32 cols
  const __hip_bfloat16* Qg =
      qkb + (rowbase + m0 + (tid >> 2)) * 3072 + (tid & 3) * 8 + QOFF;
  const __hip_bfloat16* Kg =
      qkb + (rowbase + (tid >> 2)) * 3072 + (tid & 3) * 8 + KOFF;

  float smj[4];
#pragma unroll
  for (int j = 0; j < 4; j++) {
    int col = w * 64 + j * 16 + l16;
    smj[j] = (col == 0) ? 1.f : src_mask[b * cL + col];
  }

  f4 sa[4][4], aag[4][4];
#pragma unroll
  for (int i = 0; i < 4; i++)
#pragma unroll
    for (int j = 0; j < 4; j++) {
      sa[i][j] = (f4){0.f, 0.f, 0.f, 0.f};
      aag[i][j] = (f4){0.f, 0.f, 0.f, 0.f};
    }

  auto STAGE = [&](int s, int p) {
    GLDS(Qg + s * 32, (char*)Qs[p] + (w << 10));
#pragma unroll
    for (int u = 0; u < 4; u++)
      GLDS(Kg + (long)u * 196608 + s * 32, (char*)Ks[p] + u * 4096 + (w << 10));
  };

  STAGE(0, 0);  // 5 VMEM ops/thread per stage
  STAGE(1, 1);

  for (int s = 0; s < 24; s++) {
    const int p = s & 1;
    // wait for stage(s); keep stage(s+1) in flight (except last iter)
    if (s < 23) {
      asm volatile("s_waitcnt vmcnt(5)" ::: "memory");
    } else {
      asm volatile("s_waitcnt vmcnt(0)" ::: "memory");
    }
    rbar();  // all waves' stage(s) landed
    if (!lat && (s % 3) == 0) {
#pragma unroll
      for (int i = 0; i < 4; i++)
#pragma unroll
        for (int j = 0; j < 4; j++) sa[i][j] = (f4){0.f, 0.f, 0.f, 0.f};
    }
    b8 af[4], bf[4];
#pragma unroll
    for (int i = 0; i < 4; i++)
      af[i] = *(const b8*)&Qs[p][(i * 16 + l16) * 32 + q * 8];
#pragma unroll
    for (int j = 0; j < 4; j++)
      bf[j] = *(const b8*)&Ks[p][(w * 64 + j * 16 + l16) * 32 + q * 8];
#pragma unroll
    for (int i = 0; i < 4; i++)
#pragma unroll
      for (int j = 0; j < 4; j++)
        sa[i][j] = __builtin_amdgcn_mfma_f32_16x16x32_bf16(af[i], bf[j], sa[i][j], 0, 0, 0);
    rbar();  // all waves done reading buf p
    if (s + 2 < 24) STAGE(s + 2, p);  // prefetch lands during next 2 iters
    if (!lat && (s % 3) == 2) {
      // per-head softmax (head h = s/3), cross-wave via red[], no vmcnt drain
#pragma unroll
      for (int i = 0; i < 4; i++)
#pragma unroll
        for (int j = 0; j < 4; j++)
#pragma unroll
          for (int r = 0; r < 4; r++)
            sa[i][j][r] = (smj[j] == 0.f) ? -1e9f : sa[i][j][r] * scale;
      float rm_[4][4];
#pragma unroll
      for (int i = 0; i < 4; i++)
#pragma unroll
        for (int r = 0; r < 4; r++) {
          float m = fmaxf(fmaxf(sa[i][0][r], sa[i][1][r]), fmaxf(sa[i][2][r], sa[i][3][r]));
#pragma unroll
          for (int o = 1; o < 16; o <<= 1) m = fmaxf(m, __shfl_xor(m, o, 64));
          if (l16 == 0) red[w][i * 16 + q * 4 + r] = m;
        }
      lbar();
#pragma unroll
      for (int i = 0; i < 4; i++)
#pragma unroll
        for (int r = 0; r < 4; r++) {
          int lr = i * 16 + q * 4 + r;
          rm_[i][r] = fmaxf(fmaxf(red[0][lr], red[1][lr]), fmaxf(red[2][lr], red[3][lr]));
        }
      lbar();  // max reads done before sum overwrite
#pragma unroll
      for (int i = 0; i < 4; i++)
#pragma unroll
        for (int r = 0; r < 4; r++) {
          float s0 = 0.f;
#pragma unroll
          for (int j = 0; j < 4; j++) {
            float e = expf(sa[i][j][r] - rm_[i][r]);
            sa[i][j][r] = e;
            s0 += e;
          }
#pragma unroll
          for (int o = 1; o < 16; o <<= 1) s0 += __shfl_xor(s0, o, 64);
          if (l16 == 0) red[w][i * 16 + q * 4 + r] = s0;
        }
      lbar();
#pragma unroll
      for (int i = 0; i < 4; i++)
#pragma unroll
        for (int r = 0; r < 4; r++) {
          int lr = i * 16 + q * 4 + r;
          float iv = 1.f / (red[0][lr] + red[1][lr] + red[2][lr] + red[3][lr]);
#pragma unroll
          for (int j = 0; j < 4; j++) aag[i][j][r] += sa[i][j][r] * iv;
        }
      // next red write is >=2 barriers away (next head's softmax) — safe
    }
  }

  float inv_[4][4];
  if (lat) {
    // dep metadata loaded late (short live ranges)
    int hcol[4];
    float dfc[4];
#pragma unroll
    for (int j = 0; j < 4; j++) {
      int col = w * 64 + j * 16 + l16;
      hcol[j] = (col >= 1) ? headv[b * cL + col - 1] : -1;
      dfc[j] = (col >= 1) ? df[b * cL + col - 1] : 0.f;
    }
    int hrow_[4][4];
    float dfr_[4][4];
#pragma unroll
    for (int i = 0; i < 4; i++)
#pragma unroll
      for (int r = 0; r < 4; r++) {
        int grow = m0 + i * 16 + q * 4 + r;
        hrow_[i][r] = (grow >= 1) ? headv[b * cL + grow - 1] : -1;
        dfr_[i][r] = (grow >= 1) ? df[b * cL + grow - 1] : 0.f;
      }
#pragma unroll
    for (int i = 0; i < 4; i++)
#pragma unroll
      for (int j = 0; j < 4; j++) {
        int col = w * 64 + j * 16 + l16;
#pragma unroll
        for (int r = 0; r < 4; r++) {
          int grow = m0 + i * 16 + q * 4 + r;
          float dep = 1.f;
          if (hcol[j] == grow) dep = dfc[j];
          if (col == hrow_[i][r]) dep = dfr_[i][r];
          sa[i][j][r] = sa[i][j][r] * scale + dep + (1.f - smj[j]) * -10000.f;
        }
      }
    float rm_[4][4];
#pragma unroll
    for (int i = 0; i < 4; i++)
#pragma unroll
      for (int r = 0; r < 4; r++) {
        float m = fmaxf(fmaxf(sa[i][0][r], sa[i][1][r]), fmaxf(sa[i][2][r], sa[i][3][r]));
#pragma unroll
        for (int o = 1; o < 16; o <<= 1) m = fmaxf(m, __shfl_xor(m, o, 64));
        if (l16 == 0) red[w][i * 16 + q * 4 + r] = m;
      }
    lbar();
#pragma unroll
    for (int i = 0; i < 4; i++)
#pragma unroll
      for (int r = 0; r < 4; r++) {
        int lr = i * 16 + q * 4 + r;
        rm_[i][r] = fmaxf(fmaxf(red[0][lr], red[1][lr]), fmaxf(red[2][lr], red[3][lr]));
      }
    lbar();
#pragma unroll
    for (int i = 0; i < 4; i++)
#pragma unroll
      for (int r = 0; r < 4; r++) {
        float s0 = 0.f;
#pragma unroll
        for (int j = 0; j < 4; j++) {
          float e = expf(sa[i][j][r] - rm_[i][r]);
          sa[i][j][r] = e;
          s0 += e;
        }
#pragma unroll
        for (int o = 1; o < 16; o <<= 1) s0 += __shfl_xor(s0, o, 64);
        if (l16 == 0) red[w][i * 16 + q * 4 + r] = s0;
      }
    lbar();
#pragma unroll
    for (int i = 0; i < 4; i++)
#pragma unroll
      for (int r = 0; r < 4; r++) {
        int lr = i * 16 + q * 4 + r;
        inv_[i][r] = 1.f / (red[0][lr] + red[1][lr] + red[2][lr] + red[3][lr]);
      }
  }

  float smi_[4][4];
#pragma unroll
  for (int i = 0; i < 4; i++)
#pragma unroll
    for (int r = 0; r < 4; r++) {
      int grow = m0 + i * 16 + q * 4 + r;
      smi_[i][r] = (grow == 0) ? 1.f : src_mask[b * cL + grow];
    }
  __hip_bfloat16* outA = lat ? outAlat : outAag;
#pragma unroll
  for (int j = 0; j < 4; j++) {
    int col = w * 64 + j * 16 + l16;
#pragma unroll
    for (int i = 0; i < 4; i++)
#pragma unroll
      for (int r = 0; r < 4; r++) {
        int grow = m0 + i * 16 + q * 4 + r;
        float p = lat ? sa[i][j][r] * inv_[i][r] : aag[i][j][r] * 0.125f;
        float v = (col == grow) ? 1.f : p;
        outA[((long)b * cL + grow) * cL + col] = __float2bfloat16(v * smi_[i][r]);
      }
  }
}

// -------- 7 weight convert+transpose + bias-concat (z==7) in one dispatch --------
__global__ void k_wconv7(const float* __restrict__ s0, const float* __restrict__ s1,
                         const float* __restrict__ s2, const float* __restrict__ s3,
                         const float* __restrict__ s4, const float* __restrict__ s5,
                         const float* __restrict__ s6, __hip_bfloat16* __restrict__ dst,
                         const float* __restrict__ ba, const float* __restrict__ bb,
                         const float* __restrict__ bc, const float* __restrict__ bd,
                         float* __restrict__ catb) {
  if (blockIdx.z == 7) {
    if (blockIdx.y != 0 || blockIdx.x >= 12) return;
    int tid = threadIdx.y * 32 + threadIdx.x;
    int i = blockIdx.x * 256 + tid;
    float v = (i < 768) ? ba[i] : (i < 1536) ? bb[i - 768]
              : (i < 2304) ? bc[i - 1536] : bd[i - 2304];
    catb[i] = v;
    return;
  }
  const float* srcs[7] = {s0, s1, s2, s3, s4, s5, s6};
  const float* src = srcs[blockIdx.z];
  __hip_bfloat16* d = dst + (long)blockIdx.z * cD * cD;
  __shared__ float t[32][33];
  int k0 = blockIdx.x * 32, n0 = blockIdx.y * 32;
  int tx = threadIdx.x, ty = threadIdx.y;
#pragma unroll
  for (int i = 0; i < 32; i += 8) t[ty + i][tx] = src[(long)(k0 + ty + i) * cD + n0 + tx];
  __syncthreads();
#pragma unroll
  for (int i = 0; i < 32; i += 8)
    d[(long)(n0 + ty + i) * cD + k0 + tx] = __float2bfloat16(t[tx][ty + i]);
}

// -------- embedding + layernorm + root dot, wave-per-row (bf16-only H out) --------
__global__ __launch_bounds__(256) void k_gcnin(
    const int* __restrict__ tbi, const int* __restrict__ bsi,
    const float* __restrict__ tok, const float* __restrict__ seg,
    const float* __restrict__ ln_a, const float* __restrict__ ln_b,
    const float* __restrict__ root_w, __hip_bfloat16* __restrict__ gib,
    float* __restrict__ x64, float* __restrict__ e1) {
  int wave = threadIdx.x >> 6, lane = threadIdx.x & 63;
  long bl = (long)blockIdx.x * 4 + wave;
  int t = tbi[bl], s = bsi[bl];
  const float* tr = tok + (long)t * cD;
  const float* sr = seg + (long)s * cD;
  float x[12];
  float ls = 0.f;
#pragma unroll
  for (int c = 0; c < 12; c++) {
    int d = lane + (c << 6);
    x[c] = tr[d] + sr[d];
    ls += x[c];
  }
  if ((bl & 255) == 0) {
#pragma unroll
    for (int c = 0; c < 12; c++) x64[(bl >> 8) * cD + lane + (c << 6)] = x[c];
  }
  float mean = wsum_all(ls) * (1.f / 768.f);
  float lv = 0.f;
#pragma unroll
  for (int c = 0; c < 12; c++) { float d2 = x[c] - mean; lv += d2 * d2; }
  float var = wsum_all(lv) * (1.f / 767.f);
  float inv = 1.f / (sqrtf(var) + 1e-6f);
  float rdot = 0.f;
#pragma unroll
  for (int c = 0; c < 12; c++) {
    int d = lane + (c << 6);
    float v = ln_a[d] * (x[c] - mean) * inv + ln_b[d];
    gib[bl * cD + d] = __float2bfloat16(v);
    rdot += v * root_w[d];
  }
  float tot = wsum_all(rdot);
  if (lane == 0) e1[bl] = tot;
}

// ---------------- pooled GEMV partials ----------------
__global__ __launch_bounds__(256) void k_pool1(
    const float* __restrict__ x64, const float* __restrict__ pw,
    float* __restrict__ pacc) {
  __shared__ float pws[48][256];
  __shared__ float xs[16][48];
  int i0 = blockIdx.x * 48, j0 = blockIdx.y * 256, b0 = blockIdx.z * 16;
  for (int r = 0; r < 48; r++) pws[r][threadIdx.x] = pw[(long)(i0 + r) * cD + j0 + threadIdx.x];
  for (int idx = threadIdx.x; idx < 16 * 48; idx += 256)
    xs[idx / 48][idx % 48] = x64[(long)(b0 + idx / 48) * cD + i0 + idx % 48];
  __syncthreads();
  int j = threadIdx.x;
  for (int b = 0; b < 16; b++) {
    float acc = 0.f;
#pragma unroll 8
    for (int i = 0; i < 48; i++) acc += xs[b][i] * pws[i][j];
    atomicAdd(&pacc[(long)(b0 + b) * cD + j0 + j], acc);
  }
}

// ---------------- dep LUT ----------------
__global__ __launch_bounds__(256) void k_s45(
    const float* __restrict__ dep_emb, const float* __restrict__ fc1w,
    const float* __restrict__ fc1b, const float* __restrict__ fc2w,
    const float* __restrict__ fc2b, float* __restrict__ s45) {
  int t = blockIdx.x;
  __shared__ float e[300];
  for (int i = threadIdx.x; i < 300; i += 256) e[i] = dep_emb[t * 300 + i];
  __syncthreads();
  int j = threadIdx.x;
  float h = fc1b[j];
  for (int i = 0; i < 300; i++) h += e[i] * fc1w[i * 256 + j];
  h = fmaxf(h, 0.f);
  float tot = blockSum(h * fc2w[j]);
  if (threadIdx.x == 0) s45[t] = tot + fc2b[0];
}

__global__ __launch_bounds__(256) void k_depfeat(
    const int* __restrict__ ori, const float* __restrict__ src_mask,
    const float* __restrict__ s45, float* __restrict__ dep_feat) {
  int b = blockIdx.x, l = threadIdx.x;
  float smv = (l == 0) ? 1.f : src_mask[b * cL + l];
  float sc = s45[ori[b * cL + l]] * smv + (1.f - smv) * (-1e30f);
  float mx = blockMax(sc);
  float ex = expf(sc - mx);
  float sum = blockSum(ex);
  dep_feat[b * cL + l] = ex / sum;
}

// ---------------- merged wave-per-row dots: y==0 sraw=Isem.hlsum, y==1 e2=H.vlin ----------------
__global__ __launch_bounds__(256) void k_rowdot2(
    const float* __restrict__ Isem, const float* __restrict__ hlsum,
    const float* __restrict__ gcnH, const float* __restrict__ vlin,
    float* __restrict__ sraw, float* __restrict__ e2) {
  int r = blockIdx.x * 4 + (threadIdx.x >> 6);
  int lane = threadIdx.x & 63;
  bool z = blockIdx.y != 0;
  const float4* row = (const float4*)((z ? gcnH : Isem) + (long)r * cD);
  const float4* wp = z ? (const float4*)vlin
                       : (const float4*)(hlsum + (long)(r >> 8) * cD);
  float s = 0.f;
#pragma unroll
  for (int c = 0; c < 3; c++) {
    int idx = c * 64 + lane;
    float4 a = row[idx], b = wp[idx];
    s += a.x * b.x + a.y * b.y + a.z * b.z + a.w * b.w;
  }
  s = wsum(s);
  if (lane == 0) (z ? e2 : sraw)[r] = s;
}

// -------- merged per-batch tail reductions: attn weights + root loss + lex loss --------
__global__ __launch_bounds__(256) void k_tailred(
    const float* __restrict__ sraw, const float* __restrict__ e1,
    const float* __restrict__ e2, const float* __restrict__ src_mask,
    const float* __restrict__ aspect_mask, const float* __restrict__ lex,
    float* __restrict__ wgt, float* __restrict__ asum,
    float* __restrict__ out_root, float* __restrict__ out_lex) {
  int b = blockIdx.x, l = threadIdx.x;
  float smv = (l == 0) ? 1.f : src_mask[b * cL + l];
  float am = aspect_mask[b * cL + l];
  // attn weights + asum
  float s = sraw[b * cL + l] * smv * 0.001f;
  float mx = blockMax(s);
  float ex = expf(s - mx);
  float sum = blockSum(ex);
  wgt[b * cL + l] = ex / sum;
  float a = blockSum(am);
  if (l == 0) asum[b] = a;
  // root loss
  float sc = e1[b * cL + l] * smv + (1.f - smv) * (-1e30f);
  float mx2 = blockMax(sc);
  float ex2 = expf(sc - mx2);
  float sum2 = blockSum(ex2);
  float tot = blockSum((ex2 / sum2) * am);
  if (l == 0) atomicAdd(out_root, -logf(tot + 1e-9f) * (1.f / 64.f));
  // lexicon loss
  float e = e2[b * cL + l];
  float mx3 = blockMax(e);
  float ex3 = expf(e - mx3);
  float sum3 = blockSum(ex3);
  float mult = (l == 0) ? 0.f : src_mask[b * cL + l];
  float lw = ex3 / sum3 * 50.f * mult;
  float d2 = lw - lex[b * cL + l];
  float t3 = blockSum(d2 * d2);
  if (l == 0) atomicAdd(out_lex, t3 * (1.f / (64.f * 256.f)));
}

// ---------------- hlsum partials ----------------
__global__ __launch_bounds__(256) void k_hl(
    const float* __restrict__ H, const float* __restrict__ src_mask,
    float* __restrict__ hlsum) {
  int b = blockIdx.z, d = (blockIdx.y << 8) + threadIdx.x, l0 = blockIdx.x * 32;
  float acc = 0.f;
  for (int l = l0; l < l0 + 32; l++) {
    float smv = (l == 0) ? 1.f : src_mask[b * cL + l];
    acc += H[((long)b * cL + l) * cD + d] * smv;
  }
  atomicAdd(&hlsum[(long)b * cD + d], acc);
}

// ---------------- fused outputs+sempool partials ----------------
__global__ __launch_bounds__(256) void k_wsum(
    const float* __restrict__ Isem, const float* __restrict__ wgt,
    const float* __restrict__ am, float* __restrict__ outputs,
    float* __restrict__ sempool) {
  int b = blockIdx.z, d = (blockIdx.y << 8) + threadIdx.x, l0 = blockIdx.x * 32;
  float accO = 0.f, accS = 0.f;
  for (int l = l0; l < l0 + 32; l++) {
    float v = Isem[((long)b * cL + l) * cD + d];
    accO += wgt[b * cL + l] * v;
    accS += am[b * cL + l] * v;
  }
  atomicAdd(&outputs[(long)b * cD + d], accO);
  atomicAdd(&sempool[(long)b * cD + d], accS);
}

// ---------------- logits (pooled = tanh(pacc+pb) folded in) ----------------
__global__ __launch_bounds__(256) void k_logits(
    const float* __restrict__ outputs, const float* __restrict__ sempool,
    const float* __restrict__ pacc, const float* __restrict__ pb,
    const float* __restrict__ asum, const float* __restrict__ cw,
    const float* __restrict__ cb, float* __restrict__ out) {
  int b = blockIdx.x;
  float inv = 1.f / (asum[b] + 1e-9f);
  float a0 = 0.f, a1 = 0.f, a2 = 0.f;
  for (int i = threadIdx.x; i < 3 * cD; i += 256) {
    float f;
    if (i < cD)
      f = outputs[(long)b * cD + i];
    else if (i < 2 * cD)
      f = sempool[(long)b * cD + i - cD] * inv;
    else
      f = tanhf(pacc[(long)b * cD + i - 2 * cD] + pb[i - 2 * cD]);
    a0 += f * cw[i * 3 + 0];
    a1 += f * cw[i * 3 + 1];
    a2 += f * cw[i * 3 + 2];
  }
  a0 = blockSum(a0);
  a1 = blockSum(a1);
  a2 = blockSum(a2);
  if (threadIdx.x == 0) {
    out[b * 3 + 0] = a0 + cb[0];
    out[b * 3 + 1] = a1 + cb[1];
    out[b * 3 + 2] = a2 + cb[2];
  }
}

extern "C" void kernel_launch(void* const* d_in, const int* in_sizes, int n_in,
                              void* d_out, int out_size, void* d_ws, size_t ws_size,
                              hipStream_t stream) {
  const int* tbi = (const int*)d_in[0];
  const int* bsi = (const int*)d_in[1];
  const float* src_mask = (const float*)d_in[3];
  const float* aspect_mask = (const float*)d_in[4];
  const float* lex = (const float*)d_in[5];
  const int* ori = (const int*)d_in[6];
  const int* head = (const int*)d_in[7];
  const float* tok_emb = (const float*)d_in[8];
  const float* seg_emb = (const float*)d_in[9];
  const float* pool_w = (const float*)d_in[10];
  const float* pool_b = (const float*)d_in[11];
  const float* ln_a = (const float*)d_in[12];
  const float* ln_b = (const float*)d_in[13];
  const float* dep_emb = (const float*)d_in[14];
  const float* fc1_w = (const float*)d_in[15];
  const float* fc1_b = (const float*)d_in[16];
  const float* fc2_w = (const float*)d_in[17];
  const float* fc2_b = (const float*)d_in[18];
  const float* aq_w = (const float*)d_in[19];
  const float* aq_b = (const float*)d_in[20];
  const float* ak_w = (const float*)d_in[21];
  const float* ak_b = (const float*)d_in[22];
  const float* lq_w = (const float*)d_in[23];
  const float* lq_b = (const float*)d_in[24];
  const float* lk_w = (const float*)d_in[25];
  const float* lk_b = (const float*)d_in[26];
  const float* root_w = (const float*)d_in[27];
  const float* gcn_w = (const float*)d_in[28];
  const float* gcn_b = (const float*)d_in[29];
  const float* fc3_w = (const float*)d_in[30];
  const float* fc3_b = (const float*)d_in[31];
  const float* cls_w = (const float*)d_in[32];
  const float* cls_b = (const float*)d_in[33];
  const float* vlin_w = (const float*)d_in[34];

  float* out = (float*)d_out;
  float* ws = (float*)d_ws;
  // fp32 region
  float* gcnH = ws;            // BLD (H2 f32, written by layer-1 fc3)
  float* Isem = gcnH + BLD;    // BLD
  float* depfeat = Isem + BLD;         // B*L
  float* s45 = depfeat + cB * cL;      // 64
  float* pooled = s45 + 64;            // B*D (unused)
  float* x64 = pooled + cB * cD;       // B*D
  float* hlsum = x64 + cB * cD;        // B*D  --- zeroed region start
  float* outputs = hlsum + cB * cD;    // B*D
  float* sempool = outputs + cB * cD;  // B*D
  float* pacc = sempool + cB * cD;     // B*D  --- zeroed region end
  float* e1 = pacc + cB * cD;          // B*L
  float* e2 = e1 + cB * cL;            // B*L
  float* sraw = e2 + cB * cL;          // B*L
  float* wgt = sraw + cB * cL;         // B*L
  float* asum = wgt + cB * cL;         // 64
  float* catb = asum + 64;             // 3072
  // bf16 region
  __hip_bfloat16* gib = (__hip_bfloat16*)(catb + 3072);  // BLD (H state, bf16)
  __hip_bfloat16* qkb = gib + BLD;             // 4*BLD (q|k|q2|k2, ldc=3072)
  __hip_bfloat16* scores = qkb + 4 * BLD;      // (unused, kept for layout)
  __hip_bfloat16* adjag_b = scores + 8 * BLL;  // BLL
  __hip_bfloat16* adjlat_b = adjag_b + BLL;    // BLL
  __hip_bfloat16* wbt = adjlat_b + BLL;        // 7*D*D
  // aliases
  __hip_bfloat16* HWbT = qkb + BLD;     // BLD (HW^T, written directly by EPI=4)
  __hip_bfloat16* Icb = qkb + 2 * BLD;  // BLD

  hipMemsetAsync((char*)d_out + 192 * sizeof(float), 0, 2 * sizeof(float), stream);
  hipMemsetAsync(hlsum, 0, 4 * cB * cD * sizeof(float), stream);

  // ---- prologue ----
  k_gcnin<<<cB * cL / 4, 256, 0, stream>>>(tbi, bsi, tok_emb, seg_emb, ln_a, ln_b,
                                           root_w, gib, x64, e1);
  k_s45<<<45, 256, 0, stream>>>(dep_emb, fc1_w, fc1_b, fc2_w, fc2_b, s45);
  k_depfeat<<<cB, 256, 0, stream>>>(ori, src_mask, s45, depfeat);
  k_pool1<<<dim3(16, 3, 4), 256, 0, stream>>>(x64, pool_w, pacc);
  k_wconv7<<<dim3(24, 24, 8), dim3(32, 8), 0, stream>>>(
      aq_w, ak_w, lq_w, lk_w, gcn_w, gcn_w + (long)cD * cD, fc3_w, wbt,
      aq_b, ak_b, lq_b, lk_b, catb);

  const long DD = (long)cD * cD;
  const long LD = cLD;

  // ---- fused 4-way projection: qkb = gib @ [aq|ak|lq|lk] + catb (XCD-swizzled) ----
  bgemm<1, 0, 1, 0, 1><<<dim3(24, 128, 1), 256, 0, stream>>>(
      gib, wbt, qkb, catb, nullptr, nullptr, cD, cD, cD, 3072,
      0, 0, 0, 0, 0, 0, 0, 0);

  // ---- fused adjacency builders (one dispatch, pipelined staging) ----
  k_qkadj2<<<dim3(4, cB, 2), 256, 0, stream>>>(qkb, src_mask, head, depfeat,
                                               adjag_b, adjlat_b);

  // ---- GCN loop ----
  for (int layer = 0; layer < 2; layer++) {
    const float* bb = gcn_b + (long)layer * cD;
    // HW^T = (H @ W)^T written directly (EPI=4), layout (b, d, l)
    bgemm<1, 0, 0, 4, 1><<<dim3(6, 128, 1), 256, 0, stream>>>(
        gib, wbt + (4 + layer) * DD, HWbT, nullptr, nullptr, nullptr,
        cD, cD, cD, cD, 0, 0, 0, 0, 0, 0, LD, 0);
    // dual adjacency GEMM + fused I_com epilogue (writes Isem f32 on last layer)
    bgemm_dual<<<dim3(6, 2, cB), 256, 0, stream>>>(
        adjag_b, adjlat_b, HWbT, Isem, Icb, bb, layer == 1 ? 1 : 0);
    // fc3 GEMM + H-gate epilogue on bf16 H (gib); f32 H only on last layer (tail)
    bgemm<0, 1, 1, 2, 1><<<dim3(6, 128, 1), 256, 0, stream>>>(
        Icb, wbt + 6 * DD, nullptr, fc3_b, layer == 1 ? gcnH : nullptr, gib,
        cD, cD, cD, cD, 0, 0, 0, 0, 0, 0, 0, 0);
  }

  // ---- tail ----
  k_hl<<<dim3(8, 3, cB), 256, 0, stream>>>(gcnH, src_mask, hlsum);
  k_rowdot2<<<dim3(cB * cL / 4, 2), 256, 0, stream>>>(Isem, hlsum, gcnH, vlin_w,
                                                      sraw, e2);
  k_tailred<<<cB, 256, 0, stream>>>(sraw, e1, e2, src_mask, aspect_mask, lex,
                                    wgt, asum, out + 192, out + 193);
  k_wsum<<<dim3(8, 3, cB), 256, 0, stream>>>(Isem, wgt, aspect_mask, outputs, sempool);
  k_logits<<<cB, 256, 0, stream>>>(outputs, sempool, pacc, pool_b, asum,
                                   cls_w, cls_b, out);
}